// Round 8
// baseline (361.811 us; speedup 1.0000x reference)
//
#include <hip/hip_runtime.h>
#include <math.h>

#define H 2048
#define NH 16
#define NKV 4
#define HD 128
#define BB 2
#define SS 2048
#define NT (BB*SS)           // 4096 tokens
#define NQK (NH*HD)          // 2048
#define NKVD (NKV*HD)        // 512
#define NQKV (NQK + 2*NKVD)  // 3072
#define EPSV 1e-6f
#define SM_SCALE 0.08838834764831845f
#define LOG2E 1.4426950408889634f

using s8v = __attribute__((ext_vector_type(8))) short;
using s4v = __attribute__((ext_vector_type(4))) short;
using f4v = __attribute__((ext_vector_type(4))) float;

typedef unsigned int __attribute__((address_space(1))) u32_g;
typedef unsigned int __attribute__((address_space(3))) u32_l;

__device__ inline float bf2f(short s){ unsigned u = ((unsigned)(unsigned short)s) << 16; return __builtin_bit_cast(float, u); }
__device__ inline short f2bf(float f){ unsigned u = __builtin_bit_cast(unsigned, f); u += 0x7FFF + ((u>>16)&1); return (short)(u>>16); }

__device__ inline f4v mfma16(s8v a, s8v b, f4v c){
    return __builtin_amdgcn_mfma_f32_16x16x32_bf16(a, b, c, 0, 0, 0);
}

__device__ inline void gl_lds16(const short* g, short* l){
    __builtin_amdgcn_global_load_lds((const u32_g*)g, (u32_l*)l, 16, 0, 0);
}

// ---------------- conversion / prep kernels ----------------

__global__ void cvt_f32_bf16(const float* __restrict__ in, short* __restrict__ out, int n4){
    int i = blockIdx.x*blockDim.x + threadIdx.x;
    int stride = gridDim.x*blockDim.x;
    for (; i < n4; i += stride){
        float4 v = reinterpret_cast<const float4*>(in)[i];
        s4v o = { f2bf(v.x), f2bf(v.y), f2bf(v.z), f2bf(v.w) };
        reinterpret_cast<s4v*>(out)[i] = o;
    }
}

// fp32 src [R][C] -> bf16 dst [C][R]; R, C multiples of 64
__global__ __launch_bounds__(256) void transpose_cvt(const float* __restrict__ src, short* __restrict__ dst,
                                                     int R, int C){
    __shared__ short t[64][72];
    const int tid = threadIdx.x;
    const int r0 = blockIdx.y*64, c0 = blockIdx.x*64;
    #pragma unroll
    for (int it = 0; it < 4; ++it){
        int ch = tid + it*256;
        int row = ch >> 4, c4 = (ch & 15) * 4;
        float4 v = *reinterpret_cast<const float4*>(src + (size_t)(r0+row)*C + c0 + c4);
        t[row][c4+0] = f2bf(v.x); t[row][c4+1] = f2bf(v.y);
        t[row][c4+2] = f2bf(v.z); t[row][c4+3] = f2bf(v.w);
    }
    __syncthreads();
    #pragma unroll
    for (int it = 0; it < 4; ++it){
        int ch = tid + it*256;
        int cc = ch >> 4, r4 = (ch & 15) * 4;
        s4v o = { t[r4+0][cc], t[r4+1][cc], t[r4+2][cc], t[r4+3][cc] };
        *reinterpret_cast<s4v*>(dst + (size_t)(c0+cc)*R + r0 + r4) = o;
    }
}

__global__ void concat_b(const float* __restrict__ bq, const float* __restrict__ bk,
                         const float* __restrict__ bv, float* __restrict__ Bc){
    int i = blockIdx.x*blockDim.x + threadIdx.x;
    if (i < NQKV)
        Bc[i] = (i < NQK) ? bq[i] : (i < NQK+NKVD ? bk[i-NQK] : bv[i-NQK-NKVD]);
}

// ---------------- 8-phase 256-row GEMM: C = A @ BT^T + bias ----------------
// BM=256 fixed, BN in {256,128}. 512 threads = 8 waves (2M x 4N).
// 2 LDS buffers, each one K-tile (BK=64) of A+B, XOR-swizzled (slot ^= row&7).
// Iter = 2 K-tiles: phases 1-4 compute buf0, 5-8 compute buf1.
// buf1 tile staged at p1/p2 (RAW drained by p4 vmcnt(0)+barrier);
// buf0 next tile staged at p5/p6 (WAR safe: buf0 last read at p4; RAW drained
// by p8 vmcnt(0)+barrier). All waves run identical barrier counts.

template<int BN, int OUT_F32>
__global__ __launch_bounds__(512, 2) void gemm8(const short* __restrict__ A, const short* __restrict__ BT,
                                                const float* __restrict__ bias, void* __restrict__ Cout,
                                                int M, int N, int K){
    constexpr int WN  = BN/4;       // 64 or 32 cols per wave
    constexpr int NF  = WN/16;      // 4 or 2 n-frags
    constexpr int NFH = NF/2;       // 2 or 1 n-frags per phase
    constexpr int BCH = BN/64;      // B stage chunks per thread: 4 or 2
    __shared__ short As[2][256*64];
    __shared__ short Bs[2][BN*64];
    const int tid  = threadIdx.x;
    const int lane = tid & 63;
    const int w    = tid >> 6;
    const int f    = lane & 15;
    const int g    = lane >> 4;
    const int wm   = w >> 2;
    const int wn   = w & 3;

    // XCD-aware bijective swizzle (grid sizes are multiples of 8)
    int lin = blockIdx.y * gridDim.x + blockIdx.x;
    int cpx = (gridDim.x * gridDim.y) >> 3;
    int sw  = (lin & 7) * cpx + (lin >> 3);
    const int m0 = (sw / gridDim.x) * 256;
    const int n0 = (sw % gridDim.x) * BN;

    const short* Ab = A  + (size_t)m0*K;
    const short* Bb = BT + (size_t)n0*K;

    f4v acc[8][NF] = {};

    auto STAGE_A = [&](int buf, int k0){
        #pragma unroll
        for (int c = 0; c < 4; ++c){
            int j = c*8 + w;                    // 1KB chunk 0..31
            int row = j*8 + (lane >> 3);        // 0..255
            int slot = (lane & 7) ^ (row & 7);  // pre-swizzled source
            gl_lds16(Ab + (size_t)row*K + k0 + slot*8, &As[buf][j*512]);
        }
    };
    auto STAGE_B = [&](int buf, int k0){
        #pragma unroll
        for (int c = 0; c < BCH; ++c){
            int j = c*8 + w;
            int row = j*8 + (lane >> 3);
            int slot = (lane & 7) ^ (row & 7);
            gl_lds16(Bb + (size_t)row*K + k0 + slot*8, &Bs[buf][j*512]);
        }
    };

    auto PH = [&](int buf, int qm, int qn){
        s8v a[4][2], b[NFH][2];
        #pragma unroll
        for (int mi = 0; mi < 4; ++mi){
            int row = wm*128 + (qm*4 + mi)*16 + f;
            #pragma unroll
            for (int ks = 0; ks < 2; ++ks)
                a[mi][ks] = *reinterpret_cast<const s8v*>(
                    &As[buf][row*64 + ((ks*4 + g) ^ (row & 7))*8]);
        }
        #pragma unroll
        for (int ni = 0; ni < NFH; ++ni){
            int row = wn*WN + (qn*NFH + ni)*16 + f;
            #pragma unroll
            for (int ks = 0; ks < 2; ++ks)
                b[ni][ks] = *reinterpret_cast<const s8v*>(
                    &Bs[buf][row*64 + ((ks*4 + g) ^ (row & 7))*8]);
        }
        __builtin_amdgcn_s_barrier();
        __builtin_amdgcn_s_setprio(1);
        #pragma unroll
        for (int mi = 0; mi < 4; ++mi)
            #pragma unroll
            for (int ni = 0; ni < NFH; ++ni)
                #pragma unroll
                for (int ks = 0; ks < 2; ++ks)
                    acc[qm*4 + mi][qn*NFH + ni] =
                        mfma16(a[mi][ks], b[ni][ks], acc[qm*4 + mi][qn*NFH + ni]);
        __builtin_amdgcn_s_setprio(0);
    };

    const int NITER = K >> 7;       // K/128, even K-tile count
    STAGE_A(0, 0); STAGE_B(0, 0);
    asm volatile("s_waitcnt vmcnt(0)" ::: "memory");
    __builtin_amdgcn_sched_barrier(0);
    __builtin_amdgcn_s_barrier();

    for (int it = 0; it < NITER; ++it){
        const int k0 = it*128;
        STAGE_A(1, k0 + 64);  PH(0, 0, 0);   // p1
        STAGE_B(1, k0 + 64);  PH(0, 0, 1);   // p2
        PH(0, 1, 0);                          // p3
        PH(0, 1, 1);                          // p4
        asm volatile("s_waitcnt vmcnt(0)" ::: "memory");   // buf1 landed
        __builtin_amdgcn_sched_barrier(0);
        __builtin_amdgcn_s_barrier();
        const bool pf = (it + 1 < NITER);
        if (pf) STAGE_A(0, k0 + 128);
        PH(1, 0, 0);                          // p5
        if (pf) STAGE_B(0, k0 + 128);
        PH(1, 0, 1);                          // p6
        PH(1, 1, 0);                          // p7
        PH(1, 1, 1);                          // p8
        asm volatile("s_waitcnt vmcnt(0)" ::: "memory");   // buf0 landed
        __builtin_amdgcn_sched_barrier(0);
        __builtin_amdgcn_s_barrier();
    }

    #pragma unroll
    for (int mf = 0; mf < 8; ++mf){
        #pragma unroll
        for (int nf = 0; nf < NF; ++nf){
            int col = n0 + wn*WN + nf*16 + f;
            float bvv = bias ? bias[col] : 0.f;
            #pragma unroll
            for (int r = 0; r < 4; ++r){
                int row = m0 + wm*128 + mf*16 + g*4 + r;
                float vv = acc[mf][nf][r] + bvv;
                if (OUT_F32) reinterpret_cast<float*>(Cout)[(size_t)row*N + col] = vv;
                else         reinterpret_cast<short*>(Cout)[(size_t)row*N + col] = f2bf(vv);
            }
        }
    }
}

// ---------------- fused RMSNorm + RoPE on q,k (in place, bf16) ----------------
// Q gets SM_SCALE * log2(e) folded in (attention works in exp2 domain).

__global__ __launch_bounds__(256) void norm_rope(short* __restrict__ qkv, const float* __restrict__ cosb,
                                                 const float* __restrict__ sinb, const float* __restrict__ qw,
                                                 const float* __restrict__ kw){
    int row  = blockIdx.x * 4 + (threadIdx.x >> 6);
    int lane = threadIdx.x & 63;
    const int QROWS = NT * NH;
    short* ptr; const float* w; float outscale; int token;
    if (row < QROWS){
        token = row >> 4; int h = row & 15;
        ptr = qkv + (size_t)token*NQKV + h*HD; w = qw; outscale = SM_SCALE * LOG2E;
    } else {
        int rr = row - QROWS;
        token = rr >> 2; int h = rr & 3;
        ptr = qkv + (size_t)token*NQKV + NQK + h*HD; w = kw; outscale = 1.f;
    }
    int s = token & (SS-1);
    float x1 = bf2f(ptr[lane]), x2 = bf2f(ptr[lane+64]);
    float ssq = x1*x1 + x2*x2;
    #pragma unroll
    for (int off = 32; off; off >>= 1) ssq += __shfl_xor(ssq, off, 64);
    float inv = rsqrtf(ssq * (1.f/128.f) + EPSV);
    float n1 = x1 * inv * w[lane];
    float n2 = x2 * inv * w[lane+64];
    float c1 = cosb[s*HD + lane], c2 = cosb[s*HD + lane + 64];
    float s1 = sinb[s*HD + lane], s2 = sinb[s*HD + lane + 64];
    float o1 = (n1*c1 - n2*s1) * outscale;
    float o2 = (n2*c2 + n1*s2) * outscale;
    ptr[lane]    = f2bf(o1);
    ptr[lane+64] = f2bf(o2);
}

// ---------------- tiled V transpose: qkv v-part -> Vt[b*NKVD + c][s] ----------------
// grid (SS/64, NKVD/64, BB)

__global__ __launch_bounds__(256) void vtrans(const short* __restrict__ qkv, short* __restrict__ Vt){
    __shared__ short t[64][72];
    const int tid = threadIdx.x;
    const int s0 = blockIdx.x*64, c0 = blockIdx.y*64, b = blockIdx.z;
    #pragma unroll
    for (int it = 0; it < 2; ++it){
        int ch = tid + it*256;
        int row = ch >> 3, col = (ch & 7)*8;
        s8v v = *reinterpret_cast<const s8v*>(qkv + (size_t)(b*SS + s0 + row)*NQKV + NQK + NKVD + c0 + col);
        *reinterpret_cast<s8v*>(&t[row][col]) = v;
    }
    __syncthreads();
    #pragma unroll
    for (int it = 0; it < 2; ++it){
        int ch = tid + it*256;
        int cc = ch >> 3, sc = (ch & 7)*8;
        s8v o;
        #pragma unroll
        for (int j = 0; j < 8; ++j) o[j] = t[sc + j][cc];
        *reinterpret_cast<s8v*>(Vt + (size_t)(b*NKVD + c0 + cc)*SS + s0 + sc) = o;
    }
}

// ---------------- flash attention (causal, GQA 4:1) ----------------
// grid (512); 512 threads = 8 waves. bx&7 -> (kvh,b): each XCD owns ONE KV
// stream (1 MB, L2-resident). bx>>3 -> qt heavy-first. Wave w -> head w>>1,
// row-half w&1 (16 q rows). K,V dbuf in swizzled LDS; one barrier per tile.
// Softmax: exp2 domain, defer-max (no shuffles steady-state), per-lane l.

__global__ __launch_bounds__(512, 4) void attn_fwd(const short* __restrict__ qkv, const short* __restrict__ Vt,
                                                   short* __restrict__ attn){
    __shared__ short Ks[2][8192];   // 64 keys x 128 d, XOR-swizzled  (32 KB)
    __shared__ short Vs[2][8192];   // 128 d x 64 s,  XOR-swizzled    (32 KB)
    __shared__ short Ps[8][1024];   // per-wave P: 16 q x 64 k        (16 KB)
    const int tid  = threadIdx.x;
    const int lane = tid & 63;
    const int w    = tid >> 6;
    const int f    = lane & 15;
    const int g    = lane >> 4;
    const int bx   = blockIdx.x;
    const int qt   = 63 - (bx >> 3);            // heavy tiles first
    const int kvh  = bx & 3;
    const int b    = (bx >> 2) & 1;
    const int h    = kvh*4 + (w >> 1);
    const int half = w & 1;
    const int q0   = qt * 32;                   // per-head q base
    const int qrow0 = q0 + half*16;             // this wave's 16 rows
    char* Pb = (char*)Ps[w];

    auto STAGEK = [&](int buf, int kv0){
        #pragma unroll
        for (int c = 0; c < 2; ++c){
            int issue = w + c*8;                // 0..15
            int row = issue*4 + g;              // key 0..63
            int col16 = f ^ (row & 7);
            gl_lds16(qkv + (size_t)(b*SS + kv0 + row)*NQKV + NQK + kvh*HD + col16*8,
                     &Ks[buf][issue*512]);
        }
    };
    auto STAGEV = [&](int buf, int kv0){
        #pragma unroll
        for (int c = 0; c < 2; ++c){
            int issue = w + c*8;
            int row = issue*8 + (lane >> 3);    // d 0..127
            int col16 = (lane & 7) ^ (row & 7);
            gl_lds16(Vt + (size_t)(b*NKVD + kvh*HD + row)*SS + kv0 + col16*8,
                     &Vs[buf][issue*512]);
        }
    };

    // Q fragments (A rows = f -> qrow0 + f)
    s8v qa[4];
    #pragma unroll
    for (int dc = 0; dc < 4; ++dc)
        qa[dc] = *reinterpret_cast<const s8v*>(
            qkv + (size_t)(b*SS + qrow0 + f)*NQKV + h*HD + dc*32 + g*8);

    f4v acc[8] = {};
    float m_[4], lp_[4];
    #pragma unroll
    for (int r = 0; r < 4; ++r){ m_[r] = -3e38f; lp_[r] = 0.f; }

    const int nt = (q0 + 32 + 63) >> 6;
    STAGEK(0, 0);
    STAGEV(0, 0);
    asm volatile("s_waitcnt vmcnt(0)" ::: "memory");
    __builtin_amdgcn_sched_barrier(0);
    __builtin_amdgcn_s_barrier();
    int cur = 0;

    for (int t = 0; t < nt; ++t){
        const int kv0 = t*64;
        if (t + 1 < nt){ STAGEK(cur^1, kv0 + 64); STAGEV(cur^1, kv0 + 64); }

        // ---- QK^T: sf[kh]; C: col=f=key, row=g*4+r=q-fragrow ----
        f4v sf[4] = {};
        __builtin_amdgcn_s_setprio(1);
        #pragma unroll
        for (int kh = 0; kh < 4; ++kh){
            const int krow = kh*16 + f;
            #pragma unroll
            for (int dc = 0; dc < 4; ++dc){
                s8v kb = *reinterpret_cast<const s8v*>(
                    (const char*)Ks[cur] + krow*256 + ((dc*64 + g*16) ^ ((krow & 7) << 4)));
                sf[kh] = mfma16(qa[dc], kb, sf[kh]);
            }
        }
        __builtin_amdgcn_s_setprio(0);

        // ---- causal mask ----
        if (kv0 + 63 > qrow0){
            #pragma unroll
            for (int kh = 0; kh < 4; ++kh){
                int key = kv0 + kh*16 + f;
                #pragma unroll
                for (int r = 0; r < 4; ++r){
                    int qrow = qrow0 + g*4 + r;
                    if (key > qrow) sf[kh][r] = -3e38f;
                }
            }
        }

        // ---- defer-max check: per-lane only, no cross-lane reduce ----
        float mloc[4];
        bool need = false;
        #pragma unroll
        for (int r = 0; r < 4; ++r){
            mloc[r] = fmaxf(fmaxf(sf[0][r], sf[1][r]), fmaxf(sf[2][r], sf[3][r]));
            need = need || (mloc[r] > m_[r] + 11.0f);
        }
        if (__any(need)){
            #pragma unroll
            for (int r = 0; r < 4; ++r){
                float mx = mloc[r];
                #pragma unroll
                for (int off = 8; off; off >>= 1) mx = fmaxf(mx, __shfl_xor(mx, off, 16));
                float mn = fmaxf(m_[r], mx);
                float al = __builtin_amdgcn_exp2f(m_[r] - mn);
                m_[r] = mn;
                lp_[r] *= al;
                #pragma unroll
                for (int df = 0; df < 8; ++df) acc[df][r] *= al;
            }
        }

        // ---- P = exp2(S - m) -> swizzled per-wave LDS; per-lane partial l ----
        #pragma unroll
        for (int r = 0; r < 4; ++r){
            const int prow = g*4 + r;
            #pragma unroll
            for (int kh = 0; kh < 4; ++kh){
                float p = __builtin_amdgcn_exp2f(sf[kh][r] - m_[r]);
                short pb = f2bf(p);
                lp_[r] += bf2f(pb);
                *(short*)(Pb + prow*128 + ((unsigned)((kh*16 + f)*2) ^ ((prow & 7) << 4))) = pb;
            }
        }

        // ---- PV: O += P @ V from LDS (P rows = f, V cols = d) ----
        __builtin_amdgcn_s_setprio(1);
        #pragma unroll
        for (int ks = 0; ks < 2; ++ks){
            s8v pa = *reinterpret_cast<const s8v*>(
                Pb + f*128 + ((ks*64 + g*16) ^ ((f & 7) << 4)));
            #pragma unroll
            for (int df = 0; df < 8; ++df){
                const int vrow = df*16 + f;
                s8v vb = *reinterpret_cast<const s8v*>(
                    (const char*)Vs[cur] + vrow*128 + ((ks*64 + g*16) ^ ((vrow & 7) << 4)));
                acc[df] = mfma16(pa, vb, acc[df]);
            }
        }
        __builtin_amdgcn_s_setprio(0);

        // ---- single barrier per tile ----
        asm volatile("s_waitcnt vmcnt(0)" ::: "memory");
        __builtin_amdgcn_sched_barrier(0);
        __builtin_amdgcn_s_barrier();
        cur ^= 1;
    }

    // ---- epilogue: reduce per-lane l partials across the 16 f-lanes ----
    #pragma unroll
    for (int r = 0; r < 4; ++r){
        float l = lp_[r];
        #pragma unroll
        for (int off = 8; off; off >>= 1) l += __shfl_xor(l, off, 16);
        int qrow = qrow0 + g*4 + r;
        float inv = 1.f / l;
        short* ob = attn + (size_t)(b*SS + qrow)*NQK + h*HD;
        #pragma unroll
        for (int df = 0; df < 8; ++df)
            ob[df*16 + f] = f2bf(acc[df][r] * inv);
    }
}

// ---------------- launch ----------------

extern "C" void kernel_launch(void* const* d_in, const int* in_sizes, int n_in,
                              void* d_out, int out_size, void* d_ws, size_t ws_size,
                              hipStream_t stream){
    (void)in_sizes; (void)n_in; (void)out_size; (void)ws_size;
    const float* hs   = (const float*)d_in[0];
    const float* cosb = (const float*)d_in[1];
    const float* sinb = (const float*)d_in[2];
    const float* Wq   = (const float*)d_in[3];
    const float* bq   = (const float*)d_in[4];
    const float* Wk   = (const float*)d_in[5];
    const float* bk   = (const float*)d_in[6];
    const float* Wv   = (const float*)d_in[7];
    const float* bv   = (const float*)d_in[8];
    const float* Wo   = (const float*)d_in[9];
    const float* bo   = (const float*)d_in[10];
    const float* qw   = (const float*)d_in[11];
    const float* kw   = (const float*)d_in[12];
    float* out = (float*)d_out;
    char* ws = (char*)d_ws;

    size_t off = 0;
    auto alloc = [&](size_t bytes){ size_t o = off; off += (bytes + 255) & ~(size_t)255; return o; };
    short* Xb    = (short*)(ws + alloc((size_t)NT*H*2));
    short* Wct   = (short*)(ws + alloc((size_t)NQKV*H*2));
    float* Bc    = (float*)(ws + alloc((size_t)NQKV*4));
    short* QKV   = (short*)(ws + alloc((size_t)NT*NQKV*2));
    short* Vt    = (short*)(ws + alloc((size_t)BB*NKVD*SS*2 + 4096));
    short* attnb = (short*)(ws + alloc((size_t)NT*NQK*2));
    short* WoT   = (short*)(ws + alloc((size_t)H*NQK*2));

    cvt_f32_bf16<<<2048, 256, 0, stream>>>(hs, Xb, NT*H/4);
    transpose_cvt<<<dim3(NQK/64,  H/64), 256, 0, stream>>>(Wq, Wct,                        H, NQK);
    transpose_cvt<<<dim3(NKVD/64, H/64), 256, 0, stream>>>(Wk, Wct + (size_t)NQK*H,        H, NKVD);
    transpose_cvt<<<dim3(NKVD/64, H/64), 256, 0, stream>>>(Wv, Wct + (size_t)(NQK+NKVD)*H, H, NKVD);
    transpose_cvt<<<dim3(H/64,  NQK/64), 256, 0, stream>>>(Wo, WoT,                        NQK, H);
    concat_b<<<3, 1024, 0, stream>>>(bq, bk, bv, Bc);

    gemm8<256,0><<<dim3(NQKV/256, NT/256), 512, 0, stream>>>(Xb, Wct, Bc, QKV, NT, NQKV, H);
    norm_rope<<<(NT*(NH+NKV))/4, 256, 0, stream>>>(QKV, cosb, sinb, qw, kw);
    vtrans<<<dim3(SS/64, NKVD/64, BB), 256, 0, stream>>>(QKV, Vt);
    attn_fwd<<<512, 512, 0, stream>>>(QKV, Vt, attnb);
    gemm8<128,1><<<dim3(H/128, NT/256), 512, 0, stream>>>(attnb, WoT, bo, out, NT, H, NQK);
}